// Round 11
// baseline (5638.880 us; speedup 1.0000x reference)
//
#include <hip/hip_runtime.h>
#include <stdint.h>

// FPS: B=16, C=3, N=131072, M=2048. 256 blocks (16/batch) x 1024 thr, 1/CU.
//
// R11 = R6 protocol (best: 4.13 ms) + pipelined poll + speculative centroid.
// Sync-medium measurements closed out in R8/R9/R10: plain stores, agent-scope
// atomics AND workgroup-scope atomics on global all write through to HBM
// (WRITE_SIZE arithmetic); cross-block RTT ~1.1us is a floor. So this round
// shaves what's SERIALIZED around the RTT:
//  - 4-deep rolling poll queue: checking only the oldest load lets the
//    compiler emit s_waitcnt vmcnt(3) -> detect granularity ~50 cyc instead
//    of one full load RTT (~0.9us serialized rounds in R6).
//  - Speculative centroid: on ballot success every lane holds a candidate
//    slot value; issue px/py/pz[cand] immediately, butterfly UNDER the load
//    latency, shfl the winner lane's coords, broadcast via LDS. Removes the
//    serial px[sel] L3 load and `sel` from the critical path.
// Slot reuse stays race-free (1-skew): stale in-flight loads fail the tag
// ballot; publish(t+2) requires detect(t+1) which requires all-published(t+1)
// which requires all-detected(t).
// Numerics (bit-matches XLA-CPU ref, verified R2..R10):
//   d = fma(dz,dz, fma(dy,dy, dx*dx)); key=[distBits:32][invIdx:17], tag@49.

#define NBATCH    16
#define NPTS      131072
#define SUBBLOCKS 16
#define NTHREADS  1024
#define CHUNK     8192
#define HALF      4096

typedef unsigned long long u64;

__device__ __forceinline__ u64 umax64(u64 a, u64 b) { return a > b ? a : b; }

__global__ __launch_bounds__(NTHREADS, 4)
void fps_kernel(const float* __restrict__ points,
                float* __restrict__ out,
                u64* __restrict__ slots, int M)
{
  __shared__ u64 wkeys[NTHREADS / 64];
  __shared__ __align__(16) float bc[4];   // winner coords broadcast

  const int bid   = blockIdx.x;
  const int xcd   = bid & 7;
  const int ord   = bid >> 3;
  const int batch = xcd * 2 + (ord >> 4);
  const int sub   = ord & 15;
  const int tid   = threadIdx.x;
  const int wave  = tid >> 6;
  const int lane  = tid & 63;

  const float* __restrict__ px = points + (size_t)batch * 3 * NPTS;
  const float* __restrict__ py = px + NPTS;
  const float* __restrict__ pz = px + 2 * NPTS;
  float* outb = out + (size_t)batch * 3 * M;
  u64* bslots = slots + (size_t)batch * 2 * SUBBLOCKS;

  const int cbase = sub * CHUNK;
  const int g0 = cbase + (tid << 2);
  const int g1 = g0 + HALF;

  // Load this thread's 8 points (2 x float4 per plane, coalesced).
  float4 A0 = *(const float4*)(px + g0);
  float4 B0 = *(const float4*)(py + g0);
  float4 C0 = *(const float4*)(pz + g0);
  float4 A1 = *(const float4*)(px + g1);
  float4 B1 = *(const float4*)(py + g1);
  float4 C1 = *(const float4*)(pz + g1);
  float x0=A0.x, x1=A0.y, x2=A0.z, x3=A0.w, x4=A1.x, x5=A1.y, x6=A1.z, x7=A1.w;
  float y0=B0.x, y1=B0.y, y2=B0.z, y3=B0.w, y4=B1.x, y5=B1.y, y6=B1.z, y7=B1.w;
  float z0=C0.x, z1=C0.y, z2=C0.z, z3=C0.w, z4=C1.x, z5=C1.y, z6=C1.z, z7=C1.w;
  // Pin coords (opaque to optimizer; prevents in-loop rematerialization).
  asm volatile("" :
    "+v"(x0),"+v"(x1),"+v"(x2),"+v"(x3),"+v"(x4),"+v"(x5),"+v"(x6),"+v"(x7),
    "+v"(y0),"+v"(y1),"+v"(y2),"+v"(y3),"+v"(y4),"+v"(y5),"+v"(y6),"+v"(y7),
    "+v"(z0),"+v"(z1),"+v"(z2),"+v"(z3),"+v"(z4),"+v"(z5),"+v"(z6),"+v"(z7));

  float d0, d1, d2, d3, d4, d5, d6, d7;
  d0 = d1 = d2 = d3 = d4 = d5 = d6 = d7 = __builtin_inff();

  // Iteration 0: centroid = point 0 by convention.
  float cx = px[0], cy = py[0], cz = pz[0];
  if (sub == 0 && tid == 0) { outb[0] = cx; outb[M] = cy; outb[2 * M] = cz; }

  for (int t = 1; t < M; ++t) {
    float best = -1.0f;
    int bidx = 0;
    // d = fma(dz,dz, fma(dy,dy, dx*dx)); ascending index => first-max kept.
#define STEP(XX, YY, ZZ, DREG, IDX) { \
    float dx = __fsub_rn((XX), cx); \
    float dy = __fsub_rn((YY), cy); \
    float dz = __fsub_rn((ZZ), cz); \
    float dd = __builtin_fmaf(dz, dz, __builtin_fmaf(dy, dy, __fmul_rn(dx, dx))); \
    DREG = DREG < dd ? DREG : dd; \
    if (DREG > best) { best = DREG; bidx = (IDX); } }
    STEP(x0, y0, z0, d0, g0 + 0)
    STEP(x1, y1, z1, d1, g0 + 1)
    STEP(x2, y2, z2, d2, g0 + 2)
    STEP(x3, y3, z3, d3, g0 + 3)
    STEP(x4, y4, z4, d4, g1 + 0)
    STEP(x5, y5, z5, d5, g1 + 1)
    STEP(x6, y6, z6, d6, g1 + 2)
    STEP(x7, y7, z7, d7, g1 + 3)

    // Pack [distBits:32 @17][invIdx:17 @0]; non-negative f32 bits are
    // order-preserving; invIdx breaks ties toward the SMALLEST index.
    u64 key = ((u64)__float_as_uint(best) << 17) | (u64)((NPTS - 1) - bidx);

    // Per-wave butterfly (parallel across all 16 waves).
#pragma unroll
    for (int m = 32; m >= 1; m >>= 1) {
      u64 o = __shfl_xor(key, m, 64);
      key = umax64(key, o);
    }
    if (lane == 0) wkeys[wave] = key;
    __syncthreads();

    if (wave == 0) {
      // Block reduce: lanes mirror wkeys[lane&15], 4-step butterfly.
      u64 k = wkeys[lane & 15];
#pragma unroll
      for (int m = 8; m >= 1; m >>= 1) {
        u64 o = __shfl_xor(k, m, 64);
        k = umax64(k, o);
      }
      u64* par = bslots + (size_t)(t & 1) * SUBBLOCKS;
      if (lane == 0) {
        __hip_atomic_store(par + sub, ((u64)t << 49) | k,
                           __ATOMIC_RELAXED, __HIP_MEMORY_SCOPE_AGENT);
      }

      // 4-deep pipelined converged poll: check only the OLDEST in-flight
      // load -> compiler emits s_waitcnt vmcnt(3); granularity ~ loop body.
      const u64* pp = par + (lane & 15);
#define PL() __hip_atomic_load(pp, __ATOMIC_RELAXED, __HIP_MEMORY_SCOPE_AGENT)
      u64 q0 = PL(), q1 = PL(), q2 = PL(), q3 = PL();
      u64 v;
      for (;;) {
        if (__ballot((unsigned)(q0 >> 49) == (unsigned)t) == ~0ull) { v = q0; break; }
        q0 = q1; q1 = q2; q2 = q3; q3 = PL();
      }
#undef PL

      // Speculative centroid: every lane issues loads for ITS candidate
      // immediately; the butterfly below runs under the load latency.
      int cand = (int)(NPTS - 1) - (int)(v & 0x1FFFF);
      float sx = px[cand], sy = py[cand], sz = pz[cand];

      u64 kk = v;
#pragma unroll
      for (int m = 8; m >= 1; m >>= 1) {
        u64 o = __shfl_xor(kk, m, 64);
        kk = umax64(kk, o);
      }
      // Pick the winning lane's speculative coords.
      u64 wm = __ballot(v == kk);
      int wl = (int)(__ffsll((long long)wm) - 1);
      float wxc = __shfl(sx, wl, 64);
      float wyc = __shfl(sy, wl, 64);
      float wzc = __shfl(sz, wl, 64);
      if (lane == 0) {
        bc[0] = wxc; bc[1] = wyc; bc[2] = wzc;
        if (sub == 0) {   // output write, off critical path
          outb[t]         = wxc;
          outb[M + t]     = wyc;
          outb[2 * M + t] = wzc;
        }
      }
    }
    __syncthreads();

    // All waves pick up the winner coords from LDS (~30 cyc broadcast).
    cx = bc[0]; cy = bc[1]; cz = bc[2];
  }
}

extern "C" void kernel_launch(void* const* d_in, const int* in_sizes, int n_in,
                              void* d_out, int out_size, void* d_ws, size_t ws_size,
                              hipStream_t stream) {
  (void)in_sizes; (void)n_in; (void)ws_size;
  const float* points = (const float*)d_in[0];
  float* out = (float*)d_out;
  u64* slots = (u64*)d_ws;
  const int M = out_size / (NBATCH * 3);   // 2048

  // Zero barrier slots (stale tags must not alias t in 1..M-1).
  hipMemsetAsync(d_ws, 0, (size_t)NBATCH * 2 * SUBBLOCKS * sizeof(u64), stream);

  hipLaunchKernelGGL(fps_kernel, dim3(NBATCH * SUBBLOCKS), dim3(NTHREADS), 0,
                     stream, points, out, slots, M);
}